// Round 1
// baseline (832.456 us; speedup 1.0000x reference)
//
#include <hip/hip_runtime.h>

#define N 8192
#define D 1024

typedef short bf16x8 __attribute__((ext_vector_type(8)));
typedef float f32x4 __attribute__((ext_vector_type(4)));
typedef unsigned short u16;

__device__ __forceinline__ u16 f2bf(float f) {
  unsigned u = __float_as_uint(f);
  u += 0x7FFF + ((u >> 16) & 1);   // RNE to bf16
  return (u16)(u >> 16);
}
__device__ __forceinline__ float bf2f(u16 h) {
  return __uint_as_float(((unsigned)h) << 16);
}

__device__ __forceinline__ void gload_lds16(const void* g, const void* l) {
  __builtin_amdgcn_global_load_lds(
      (const __attribute__((address_space(1))) void*)g,
      (__attribute__((address_space(3))) void*)l, 16, 0, 0);
}

// ---------------- K0: split X (fp32) into Hi/Lo bf16 ----------------
__global__ __launch_bounds__(256) void k_split(const float* __restrict__ X,
                                               u16* __restrict__ hi,
                                               u16* __restrict__ lo) {
  int i = blockIdx.x * 256 + threadIdx.x;   // float4 index, total N*D/4
  float4 x = ((const float4*)X)[i];
  u16 h0 = f2bf(x.x), h1 = f2bf(x.y), h2 = f2bf(x.z), h3 = f2bf(x.w);
  ushort4 hv = {h0, h1, h2, h3};
  ushort4 lv = {f2bf(x.x - bf2f(h0)), f2bf(x.y - bf2f(h1)),
                f2bf(x.z - bf2f(h2)), f2bf(x.w - bf2f(h3))};
  ((ushort4*)hi)[i] = hv;
  ((ushort4*)lo)[i] = lv;
}

// ---------------- K0b: transpose Xhi [N][D] -> XT [D][N] ----------------
__global__ __launch_bounds__(256) void k_transpose(const u16* __restrict__ Xh,
                                                   u16* __restrict__ XT) {
  __shared__ u16 t[32][33];
  const int jt = blockIdx.y * 32, dt = blockIdx.x * 32;
  const int c = threadIdx.x & 31, rg = threadIdx.x >> 5;   // rg in 0..7
#pragma unroll
  for (int k = 0; k < 4; ++k) {
    int r = rg * 4 + k;
    t[r][c] = Xh[(size_t)(jt + r) * D + dt + c];
  }
  __syncthreads();
#pragma unroll
  for (int k = 0; k < 4; ++k) {
    int d = rg * 4 + k;
    XT[(size_t)(dt + d) * N + jt + c] = t[c][d];
  }
}

// ---------------- K1: S = X X^T via 3-GEMM bf16 split (fp32-accurate) ----
__global__ __launch_bounds__(256) void k_qkt(const u16* __restrict__ Xh,
                                             const u16* __restrict__ Xl,
                                             float* __restrict__ S) {
  __shared__ u16 Ah[128 * 32], Al[128 * 32], Bh[128 * 32], Bl[128 * 32];
  const int tid = threadIdx.x, wid = tid >> 6, lane = tid & 63;
  const int brow = blockIdx.y * 128, bcol = blockIdx.x * 128;
  const int wr = wid >> 1, wc = wid & 1;
  const int fr = lane & 15, koff = (lane >> 4) * 8;

  f32x4 acc[4][4] = {};

  for (int kt = 0; kt < D; kt += 32) {
    __syncthreads();
    // stage 4 tiles (128x32 bf16 each); per wave: 2 chunks of 1024B per tile
#pragma unroll
    for (int c = 0; c < 2; ++c) {
      int chunk = wid * 2 + c;         // 0..7
      int e = chunk * 512;             // element base of this 1024B chunk
      int row = (e + lane * 8) >> 5;
      int col = (e + lane * 8) & 31;
      size_t ga = (size_t)(brow + row) * D + kt + col;
      size_t gb = (size_t)(bcol + row) * D + kt + col;
      gload_lds16(Xh + ga, (const u16*)Ah + e);
      gload_lds16(Xl + ga, (const u16*)Al + e);
      gload_lds16(Xh + gb, (const u16*)Bh + e);
      gload_lds16(Xl + gb, (const u16*)Bl + e);
    }
    __syncthreads();

    bf16x8 ah[4], al[4], bh[4], bl[4];
#pragma unroll
    for (int m = 0; m < 4; ++m) {
      int r = (wr * 64 + m * 16 + fr) * 32 + koff;
      ah[m] = *(const bf16x8*)&Ah[r];
      al[m] = *(const bf16x8*)&Al[r];
    }
#pragma unroll
    for (int n = 0; n < 4; ++n) {
      int r = (wc * 64 + n * 16 + fr) * 32 + koff;
      bh[n] = *(const bf16x8*)&Bh[r];
      bl[n] = *(const bf16x8*)&Bl[r];
    }
#pragma unroll
    for (int m = 0; m < 4; ++m)
#pragma unroll
      for (int n = 0; n < 4; ++n) {
        acc[m][n] = __builtin_amdgcn_mfma_f32_16x16x32_bf16(ah[m], bh[n], acc[m][n], 0, 0, 0);
        acc[m][n] = __builtin_amdgcn_mfma_f32_16x16x32_bf16(ah[m], bl[n], acc[m][n], 0, 0, 0);
        acc[m][n] = __builtin_amdgcn_mfma_f32_16x16x32_bf16(al[m], bh[n], acc[m][n], 0, 0, 0);
      }
  }

  const int rr = (lane >> 4) * 4;
#pragma unroll
  for (int m = 0; m < 4; ++m)
#pragma unroll
    for (int n = 0; n < 4; ++n)
#pragma unroll
      for (int r = 0; r < 4; ++r) {
        int row = brow + wr * 64 + m * 16 + rr + r;
        int col = bcol + wc * 64 + n * 16 + fr;
        S[(size_t)row * N + col] = acc[m][n][r];
      }
}

// ---------------- K2: in-place row softmax, diag -> -inf -> 0 ----------
__global__ __launch_bounds__(256) void k_softmax(float* __restrict__ S) {
  const int row = blockIdx.x;
  float* p = S + (size_t)row * N;
  const int tid = threadIdx.x;
  const int wid = tid >> 6, lane = tid & 63;
  __shared__ float red[4];

  float4 v[8];
  float m = -INFINITY;
#pragma unroll
  for (int i = 0; i < 8; ++i) {
    int idx = i * 256 + tid;              // float4 index within row
    float4 x = ((const float4*)p)[idx];
    if ((row >> 2) == idx) ((float*)&x)[row & 3] = -INFINITY;  // exclude diag
    v[i] = x;
    m = fmaxf(m, fmaxf(fmaxf(x.x, x.y), fmaxf(x.z, x.w)));
  }
#pragma unroll
  for (int off = 32; off > 0; off >>= 1) m = fmaxf(m, __shfl_xor(m, off));
  if (lane == 0) red[wid] = m;
  __syncthreads();
  m = fmaxf(fmaxf(red[0], red[1]), fmaxf(red[2], red[3]));

  float s = 0.f;
#pragma unroll
  for (int i = 0; i < 8; ++i) {
    float4 e;
    e.x = __expf(v[i].x - m);
    e.y = __expf(v[i].y - m);
    e.z = __expf(v[i].z - m);
    e.w = __expf(v[i].w - m);
    v[i] = e;
    s += e.x + e.y + e.z + e.w;
  }
#pragma unroll
  for (int off = 32; off > 0; off >>= 1) s += __shfl_xor(s, off);
  __syncthreads();                        // red[] reuse
  if (lane == 0) red[wid] = s;
  __syncthreads();
  s = red[0] + red[1] + red[2] + red[3];
  float inv = 1.0f / s;
#pragma unroll
  for (int i = 0; i < 8; ++i) {
    int idx = i * 256 + tid;
    float4 x = v[i];
    x.x *= inv; x.y *= inv; x.z *= inv; x.w *= inv;
    ((float4*)p)[idx] = x;
  }
}

// ---------------- K3: out = P @ X  (P fp32 -> bf16 reg-staged; X = XT bf16)
__global__ __launch_bounds__(256) void k_pv(const float* __restrict__ P,
                                            const u16* __restrict__ XT,
                                            float* __restrict__ Out) {
  __shared__ u16 As[128 * 32], Bs[128 * 32];
  const int tid = threadIdx.x, wid = tid >> 6, lane = tid & 63;
  const int brow = blockIdx.y * 128;   // rows of P / out
  const int bcol = blockIdx.x * 128;   // cols of out (d)
  const int wr = wid >> 1, wc = wid & 1;
  const int fr = lane & 15, koff = (lane >> 4) * 8;

  f32x4 acc[4][4] = {};

  for (int kt = 0; kt < N; kt += 32) {
    __syncthreads();
    // stage B = XT[bcol..+128][kt..+32] (bf16, async direct to LDS)
#pragma unroll
    for (int c = 0; c < 2; ++c) {
      int chunk = wid * 2 + c;
      int e = chunk * 512;
      int row = (e + lane * 8) >> 5;
      int col = (e + lane * 8) & 31;
      gload_lds16(XT + (size_t)(bcol + row) * N + kt + col, (const u16*)Bs + e);
    }
    // stage A = P[brow..+128][kt..+32] fp32 -> bf16 (reg-staged)
#pragma unroll
    for (int i = 0; i < 4; ++i) {
      int idx = i * 256 + tid;           // float4 index in 128x32 tile
      int e = idx * 4;
      int row = e >> 5, col = e & 31;
      float4 x = *(const float4*)(P + (size_t)(brow + row) * N + kt + col);
      ushort4 h = {f2bf(x.x), f2bf(x.y), f2bf(x.z), f2bf(x.w)};
      *(ushort4*)&As[e] = h;
    }
    __syncthreads();

    bf16x8 a[4], b[4];
#pragma unroll
    for (int m = 0; m < 4; ++m)
      a[m] = *(const bf16x8*)&As[(wr * 64 + m * 16 + fr) * 32 + koff];
#pragma unroll
    for (int n = 0; n < 4; ++n)
      b[n] = *(const bf16x8*)&Bs[(wc * 64 + n * 16 + fr) * 32 + koff];
#pragma unroll
    for (int m = 0; m < 4; ++m)
#pragma unroll
      for (int n = 0; n < 4; ++n)
        acc[m][n] = __builtin_amdgcn_mfma_f32_16x16x32_bf16(a[m], b[n], acc[m][n], 0, 0, 0);
  }

  const int rr = (lane >> 4) * 4;
#pragma unroll
  for (int m = 0; m < 4; ++m)
#pragma unroll
    for (int n = 0; n < 4; ++n)
#pragma unroll
      for (int r = 0; r < 4; ++r) {
        int row = brow + wr * 64 + m * 16 + rr + r;
        int col = bcol + wc * 64 + n * 16 + fr;
        Out[(size_t)row * D + col] = acc[m][n][r];
      }
}

extern "C" void kernel_launch(void* const* d_in, const int* in_sizes, int n_in,
                              void* d_out, int out_size, void* d_ws, size_t ws_size,
                              hipStream_t stream) {
  const float* X = (const float*)d_in[0];
  float* out = (float*)d_out;
  float* attn = out + (size_t)N * D;        // second output, raw S then softmaxed

  u16* Xh = (u16*)d_ws;                     // 16 MB
  u16* Xl = Xh + (size_t)N * D;             // 16 MB
  u16* XT = Xl + (size_t)N * D;             // 16 MB  (total 48 MB of d_ws)

  k_split<<<(N * D / 4) / 256, 256, 0, stream>>>(X, Xh, Xl);
  k_transpose<<<dim3(D / 32, N / 32), 256, 0, stream>>>(Xh, XT);
  k_qkt<<<dim3(N / 128, N / 128), 256, 0, stream>>>(Xh, Xl, attn);
  k_softmax<<<N, 256, 0, stream>>>(attn);
  k_pv<<<dim3(D / 128, N / 128), 256, 0, stream>>>(attn, XT, out);
}

// Round 2
// 659.729 us; speedup vs baseline: 1.2618x; 1.2618x over previous
//
#include <hip/hip_runtime.h>

#define N 8192
#define D 1024

typedef short bf16x8 __attribute__((ext_vector_type(8)));
typedef float f32x4 __attribute__((ext_vector_type(4)));
typedef unsigned short u16;

__device__ __forceinline__ u16 f2bf(float f) {
  unsigned u = __float_as_uint(f);
  u += 0x7FFF + ((u >> 16) & 1);   // RNE to bf16
  return (u16)(u >> 16);
}
__device__ __forceinline__ float bf2f(u16 h) {
  return __uint_as_float(((unsigned)h) << 16);
}

__device__ __forceinline__ void gload_lds16(const void* g, const void* l) {
  __builtin_amdgcn_global_load_lds(
      (const __attribute__((address_space(1))) void*)g,
      (__attribute__((address_space(3))) void*)l, 16, 0, 0);
}

// ---------------- K0: split X (fp32) into Hi/Lo bf16 ----------------
__global__ __launch_bounds__(256) void k_split(const float* __restrict__ X,
                                               u16* __restrict__ hi,
                                               u16* __restrict__ lo) {
  int i = blockIdx.x * 256 + threadIdx.x;   // float4 index, total N*D/4
  float4 x = ((const float4*)X)[i];
  u16 h0 = f2bf(x.x), h1 = f2bf(x.y), h2 = f2bf(x.z), h3 = f2bf(x.w);
  ushort4 hv = {h0, h1, h2, h3};
  ushort4 lv = {f2bf(x.x - bf2f(h0)), f2bf(x.y - bf2f(h1)),
                f2bf(x.z - bf2f(h2)), f2bf(x.w - bf2f(h3))};
  ((ushort4*)hi)[i] = hv;
  ((ushort4*)lo)[i] = lv;
}

// ---------------- K0b: transpose Xhi [N][D] -> XT [D][N] ----------------
__global__ __launch_bounds__(256) void k_transpose(const u16* __restrict__ Xh,
                                                   u16* __restrict__ XT) {
  __shared__ u16 t[32][33];
  const int jt = blockIdx.y * 32, dt = blockIdx.x * 32;
  const int c = threadIdx.x & 31, rg = threadIdx.x >> 5;   // rg in 0..7
#pragma unroll
  for (int k = 0; k < 4; ++k) {
    int r = rg * 4 + k;
    t[r][c] = Xh[(size_t)(jt + r) * D + dt + c];
  }
  __syncthreads();
#pragma unroll
  for (int k = 0; k < 4; ++k) {
    int d = rg * 4 + k;
    XT[(size_t)(dt + d) * N + jt + c] = t[c][d];
  }
}

// ------- K1: S = X X^T, symmetric: only upper-tri 128x128 blocks --------
__global__ __launch_bounds__(256) void k_qkt(const u16* __restrict__ Xh,
                                             const u16* __restrict__ Xl,
                                             float* __restrict__ S) {
  __shared__ union {
    u16 stage[4][128 * 32];     // Ah, Al, Bh, Bl
    float tbuf[128][68];        // transpose bounce (68: 16B-aligned rows, bank-spread)
  } sm;
  u16* Ah = sm.stage[0];
  u16* Al = sm.stage[1];
  u16* Bh = sm.stage[2];
  u16* Bl = sm.stage[3];

  const int tid = threadIdx.x, wid = tid >> 6, lane = tid & 63;

  // map linear block id -> (bi, bj), bi <= bj, over 64x64 block grid
  int t = blockIdx.x, bi = 0;
  while (t >= 64 - bi) { t -= 64 - bi; ++bi; }
  const int bj = bi + t;
  const int brow = bi * 128, bcol = bj * 128;

  const int wr = wid >> 1, wc = wid & 1;
  const int fr = lane & 15, koff = (lane >> 4) * 8;

  f32x4 acc[4][4] = {};

  for (int kt = 0; kt < D; kt += 32) {
    __syncthreads();
#pragma unroll
    for (int c = 0; c < 2; ++c) {
      int chunk = wid * 2 + c;         // 0..7
      int e = chunk * 512;             // element base of this 1024B chunk
      int row = (e + lane * 8) >> 5;
      int col = (e + lane * 8) & 31;
      size_t ga = (size_t)(brow + row) * D + kt + col;
      size_t gb = (size_t)(bcol + row) * D + kt + col;
      gload_lds16(Xh + ga, Ah + e);
      gload_lds16(Xl + ga, Al + e);
      gload_lds16(Xh + gb, Bh + e);
      gload_lds16(Xl + gb, Bl + e);
    }
    __syncthreads();

    bf16x8 ah[4], al[4], bh[4], bl[4];
#pragma unroll
    for (int m = 0; m < 4; ++m) {
      int r = (wr * 64 + m * 16 + fr) * 32 + koff;
      ah[m] = *(const bf16x8*)&Ah[r];
      al[m] = *(const bf16x8*)&Al[r];
    }
#pragma unroll
    for (int n = 0; n < 4; ++n) {
      int r = (wc * 64 + n * 16 + fr) * 32 + koff;
      bh[n] = *(const bf16x8*)&Bh[r];
      bl[n] = *(const bf16x8*)&Bl[r];
    }
#pragma unroll
    for (int m = 0; m < 4; ++m)
#pragma unroll
      for (int n = 0; n < 4; ++n) {
        acc[m][n] = __builtin_amdgcn_mfma_f32_16x16x32_bf16(ah[m], bh[n], acc[m][n], 0, 0, 0);
        acc[m][n] = __builtin_amdgcn_mfma_f32_16x16x32_bf16(ah[m], bl[n], acc[m][n], 0, 0, 0);
        acc[m][n] = __builtin_amdgcn_mfma_f32_16x16x32_bf16(al[m], bh[n], acc[m][n], 0, 0, 0);
      }
  }

  const int rr = (lane >> 4) * 4;
  // direct tile write: S[brow..][bcol..]
#pragma unroll
  for (int m = 0; m < 4; ++m)
#pragma unroll
    for (int n = 0; n < 4; ++n)
#pragma unroll
      for (int r = 0; r < 4; ++r) {
        int row = brow + wr * 64 + m * 16 + rr + r;
        int col = bcol + wc * 64 + n * 16 + fr;
        S[(size_t)row * N + col] = acc[m][n][r];
      }

  // transposed tile write for off-diagonal blocks: S[bcol..][brow..]
  if (bi != bj) {
#pragma unroll
    for (int pass = 0; pass < 2; ++pass) {
      __syncthreads();                 // stage/tbuf reuse + pass-0 reads done
      if (wr == pass) {
#pragma unroll
        for (int m = 0; m < 4; ++m)
#pragma unroll
          for (int n = 0; n < 4; ++n) {
            f32x4 v = acc[m][n];
            int c = wc * 64 + n * 16 + fr;
            *(f32x4*)&sm.tbuf[c][m * 16 + rr] = v;   // rows rel. to pass*64
          }
      }
      __syncthreads();
#pragma unroll
      for (int i = 0; i < 8; ++i) {
        int idx = i * 256 + tid;         // 2048 float4 = 128 cols x 16 quads
        int c = idx >> 4;                // 0..127
        int kq = idx & 15;               // 0..15
        float4 v4 = *(const float4*)&sm.tbuf[c][kq * 4];
        *(float4*)&S[(size_t)(bcol + c) * N + brow + pass * 64 + kq * 4] = v4;
      }
    }
  }
}

// ---------------- K2: in-place row softmax (+ optional bf16 P copy) -----
template <int WRITE_PB>
__global__ __launch_bounds__(256) void k_softmax(float* __restrict__ S,
                                                 u16* __restrict__ Pb) {
  const int row = blockIdx.x;
  float* p = S + (size_t)row * N;
  const int tid = threadIdx.x;
  const int wid = tid >> 6, lane = tid & 63;
  __shared__ float red[4];

  float4 v[8];
  float m = -INFINITY;
#pragma unroll
  for (int i = 0; i < 8; ++i) {
    int idx = i * 256 + tid;              // float4 index within row
    float4 x = ((const float4*)p)[idx];
    if ((row >> 2) == idx) ((float*)&x)[row & 3] = -INFINITY;  // exclude diag
    v[i] = x;
    m = fmaxf(m, fmaxf(fmaxf(x.x, x.y), fmaxf(x.z, x.w)));
  }
#pragma unroll
  for (int off = 32; off > 0; off >>= 1) m = fmaxf(m, __shfl_xor(m, off));
  if (lane == 0) red[wid] = m;
  __syncthreads();
  m = fmaxf(fmaxf(red[0], red[1]), fmaxf(red[2], red[3]));

  float s = 0.f;
#pragma unroll
  for (int i = 0; i < 8; ++i) {
    float4 e;
    e.x = __expf(v[i].x - m);
    e.y = __expf(v[i].y - m);
    e.z = __expf(v[i].z - m);
    e.w = __expf(v[i].w - m);
    v[i] = e;
    s += e.x + e.y + e.z + e.w;
  }
#pragma unroll
  for (int off = 32; off > 0; off >>= 1) s += __shfl_xor(s, off);
  __syncthreads();                        // red[] reuse
  if (lane == 0) red[wid] = s;
  __syncthreads();
  s = red[0] + red[1] + red[2] + red[3];
  float inv = 1.0f / s;
#pragma unroll
  for (int i = 0; i < 8; ++i) {
    int idx = i * 256 + tid;
    float4 x = v[i];
    x.x *= inv; x.y *= inv; x.z *= inv; x.w *= inv;
    ((float4*)p)[idx] = x;
    if (WRITE_PB) {
      ushort4 h = {f2bf(x.x), f2bf(x.y), f2bf(x.z), f2bf(x.w)};
      ((ushort4*)(Pb + (size_t)row * N))[idx] = h;
    }
  }
}

// ---------------- K3: out = P @ X  (A from bf16 Pb if available) --------
template <int BF16P>
__global__ __launch_bounds__(256) void k_pv(const float* __restrict__ P,
                                            const u16* __restrict__ Pb,
                                            const u16* __restrict__ XT,
                                            float* __restrict__ Out) {
  __shared__ u16 As[128 * 32], Bs[128 * 32];
  const int tid = threadIdx.x, wid = tid >> 6, lane = tid & 63;
  const int brow = blockIdx.y * 128;   // rows of P / out
  const int bcol = blockIdx.x * 128;   // cols of out (d)
  const int wr = wid >> 1, wc = wid & 1;
  const int fr = lane & 15, koff = (lane >> 4) * 8;

  f32x4 acc[4][4] = {};

  for (int kt = 0; kt < N; kt += 32) {
    __syncthreads();
    // stage B = XT[bcol..+128][kt..+32] (bf16, async direct to LDS)
#pragma unroll
    for (int c = 0; c < 2; ++c) {
      int chunk = wid * 2 + c;
      int e = chunk * 512;
      int row = (e + lane * 8) >> 5;
      int col = (e + lane * 8) & 31;
      gload_lds16(XT + (size_t)(bcol + row) * N + kt + col, (const u16*)Bs + e);
      if (BF16P) {
        gload_lds16(Pb + (size_t)(brow + row) * N + kt + col, (const u16*)As + e);
      }
    }
    if (!BF16P) {
      // stage A = P[brow..+128][kt..+32] fp32 -> bf16 (reg-staged)
#pragma unroll
      for (int i = 0; i < 4; ++i) {
        int idx = i * 256 + tid;           // float4 index in 128x32 tile
        int e = idx * 4;
        int row = e >> 5, col = e & 31;
        float4 x = *(const float4*)(P + (size_t)(brow + row) * N + kt + col);
        ushort4 h = {f2bf(x.x), f2bf(x.y), f2bf(x.z), f2bf(x.w)};
        *(ushort4*)&As[e] = h;
      }
    }
    __syncthreads();

    bf16x8 a[4], b[4];
#pragma unroll
    for (int m = 0; m < 4; ++m)
      a[m] = *(const bf16x8*)&As[(wr * 64 + m * 16 + fr) * 32 + koff];
#pragma unroll
    for (int n = 0; n < 4; ++n)
      b[n] = *(const bf16x8*)&Bs[(wc * 64 + n * 16 + fr) * 32 + koff];
#pragma unroll
    for (int m = 0; m < 4; ++m)
#pragma unroll
      for (int n = 0; n < 4; ++n)
        acc[m][n] = __builtin_amdgcn_mfma_f32_16x16x32_bf16(a[m], b[n], acc[m][n], 0, 0, 0);
  }

  const int rr = (lane >> 4) * 4;
#pragma unroll
  for (int m = 0; m < 4; ++m)
#pragma unroll
    for (int n = 0; n < 4; ++n)
#pragma unroll
      for (int r = 0; r < 4; ++r) {
        int row = brow + wr * 64 + m * 16 + rr + r;
        int col = bcol + wc * 64 + n * 16 + fr;
        Out[(size_t)row * D + col] = acc[m][n][r];
      }
}

extern "C" void kernel_launch(void* const* d_in, const int* in_sizes, int n_in,
                              void* d_out, int out_size, void* d_ws, size_t ws_size,
                              hipStream_t stream) {
  const float* X = (const float*)d_in[0];
  float* out = (float*)d_out;
  float* attn = out + (size_t)N * D;        // second output: raw S, then softmaxed

  u16* Xh = (u16*)d_ws;                     // 16 MB
  u16* Xl = Xh + (size_t)N * D;             // 16 MB
  u16* XT = Xl + (size_t)N * D;             // 16 MB
  u16* Pb = XT + (size_t)N * D;             // 128 MB (optional)
  const bool usePb =
      ws_size >= ((size_t)N * D * 3 + (size_t)N * N) * sizeof(u16);

  k_split<<<(N * D / 4) / 256, 256, 0, stream>>>(X, Xh, Xl);
  k_transpose<<<dim3(D / 32, N / 32), 256, 0, stream>>>(Xh, XT);
  k_qkt<<<64 * 65 / 2, 256, 0, stream>>>(Xh, Xl, attn);
  if (usePb) {
    k_softmax<1><<<N, 256, 0, stream>>>(attn, Pb);
    k_pv<1><<<dim3(D / 128, N / 128), 256, 0, stream>>>(attn, Pb, XT, out);
  } else {
    k_softmax<0><<<N, 256, 0, stream>>>(attn, nullptr);
    k_pv<0><<<dim3(D / 128, N / 128), 256, 0, stream>>>(attn, nullptr, XT, out);
  }
}